// Round 4
// baseline (64.506 us; speedup 1.0000x reference)
//
#include <hip/hip_runtime.h>
#include <math.h>

#define D 8
#define H 16
#define HD 128

__device__ __forceinline__ float sigmoidf(float x) {
    return 1.0f / (1.0f + expf(-x));
}

// One thread per (row n, quad q): handles h = 4q .. 4q+3 via float4.
// out[n, i*16 + h] = q_mu[n, i*16 + h] + sum_{j<=i} L_n[i][j] * eps[n, j*16 + h]
// where L_n = chol( s_n*(t t^T + c) + 1e-6 I ), an 8x8 lower factor.
// (chol(kron(A, I_H)) = kron(chol(A), I_H) collapses the reference's 128x128
// batched Cholesky to this per-row 8x8 one.)
__global__ __launch_bounds__(64) void vdlv_kernel(
    const float* __restrict__ q_mu,
    const float* __restrict__ q_dim_v,
    const float* __restrict__ q_dim_B,
    const float* __restrict__ q_time_var,
    const float* __restrict__ eps,
    float* __restrict__ out,
    int n_rows)
{
    int gid = blockIdx.x * blockDim.x + threadIdx.x;
    if (gid >= n_rows * 4) return;
    int n = gid >> 2;   // row
    int q = gid & 3;    // float4 index within the H=16 slice

    // Shared small parameters (broadcast loads, cached)
    float c = sigmoidf(q_dim_v[0]);
    float t[D];
#pragma unroll
    for (int i = 0; i < D; ++i) t[i] = 2.0f * sigmoidf(q_dim_B[i]) - 1.0f;
    float s = sigmoidf(q_time_var[n]);

    // M = s*(t t^T + c*11^T) + 1e-6 I (lower triangle), Cholesky in place.
    // Fully unrolled -> register-resident (static indexing only).
    float L[D][D];
#pragma unroll
    for (int i = 0; i < D; ++i) {
#pragma unroll
        for (int j = 0; j <= i; ++j) {
            L[i][j] = s * (t[i] * t[j] + c) + ((i == j) ? 1e-6f : 0.0f);
        }
    }

#pragma unroll
    for (int k = 0; k < D; ++k) {
        float d = L[k][k];
#pragma unroll
        for (int m = 0; m < k; ++m) d -= L[k][m] * L[k][m];
        d = sqrtf(d);
        L[k][k] = d;
        float inv = 1.0f / d;
#pragma unroll
        for (int i = k + 1; i < D; ++i) {
            float v = L[i][k];
#pragma unroll
            for (int m = 0; m < k; ++m) v -= L[i][m] * L[k][m];
            L[i][k] = v * inv;
        }
    }

    // float4-vectorized triangular matvec over the 4 h-slots of this quad.
    // Row base: n*HD floats (512 B, 16B-aligned); quad offset q*4 floats.
    const float4* __restrict__ erow = (const float4*)(eps  + (size_t)n * HD) + q;
    const float4* __restrict__ mrow = (const float4*)(q_mu + (size_t)n * HD) + q;
    float4* __restrict__ orow       = (float4*)(out  + (size_t)n * HD) + q;

    float4 e[D];
#pragma unroll
    for (int j = 0; j < D; ++j) e[j] = erow[j * (H / 4)];

#pragma unroll
    for (int i = 0; i < D; ++i) {
        float4 acc = mrow[i * (H / 4)];
#pragma unroll
        for (int j = 0; j <= i; ++j) {
            float lij = L[i][j];
            acc.x = fmaf(lij, e[j].x, acc.x);
            acc.y = fmaf(lij, e[j].y, acc.y);
            acc.z = fmaf(lij, e[j].z, acc.z);
            acc.w = fmaf(lij, e[j].w, acc.w);
        }
        orow[i * (H / 4)] = acc;
    }
}

extern "C" void kernel_launch(void* const* d_in, const int* in_sizes, int n_in,
                              void* d_out, int out_size, void* d_ws, size_t ws_size,
                              hipStream_t stream) {
    const float* q_mu       = (const float*)d_in[0];
    const float* q_dim_v    = (const float*)d_in[1];
    const float* q_dim_B    = (const float*)d_in[2];
    const float* q_time_var = (const float*)d_in[3];
    const float* eps        = (const float*)d_in[4];
    float* out              = (float*)d_out;

    int n_rows = in_sizes[3];           // N from q_time_var
    int total  = n_rows * 4;            // one thread per (n, h-quad)
    int block  = 64;                    // 1 wave per block -> spread across CUs
    int grid   = (total + block - 1) / block;

    vdlv_kernel<<<grid, block, 0, stream>>>(q_mu, q_dim_v, q_dim_B, q_time_var,
                                            eps, out, n_rows);
}